// Round 18
// baseline (98.784 us; speedup 1.0000x reference)
//
#include <hip/hip_runtime.h>
#include <cstdint>
#include <cstddef>

// DeformConv2d B=8 C=256 H=W=64 Cout=256 K=3 s=1 p=1 d=1
// Round 18 = Round 16 (dbuf cols, 1 barrier/chunk, 76us main) + T14
// issue-early on ONE gather task (e0): loads issued before the MFMA
// section, interp+ds_write after it (before the barrier). Payload = 16
// VGPR held across MFMA -> peak ~56 regs, under the (1024,8) 64-cap
// (r14/r15 spill lesson: only one task's payload). e1/e2 inline as r16.
// Fallback (ws too small): round-6 proven kernel.

#define B_   8
#define C_   256
#define H_   64
#define W_   64
#define CO_  256
#define KK_  9
#define BUFSZ (4 * 9 * 512)          // shorts per cols buffer

typedef short    short8 __attribute__((ext_vector_type(8)));
typedef float    f32x4  __attribute__((ext_vector_type(4)));

__device__ inline short f2bf(float f) {   // round-to-nearest-even fp32->bf16
    uint32_t u = __builtin_bit_cast(uint32_t, f);
    u += 0x7FFFu + ((u >> 16) & 1u);
    return (short)(u >> 16);
}
__device__ inline float bf2f(short s) {
    return __builtin_bit_cast(float, (uint32_t)(uint16_t)s << 16);
}
__device__ inline float lof(uint32_t u) {
    return __builtin_bit_cast(float, u << 16);
}
__device__ inline float hif(uint32_t u) {
    return __builtin_bit_cast(float, u & 0xFFFF0000u);
}

// ---- prepass 1: weight fp32 -> bf16 in A-FRAGMENT order ----
// entry i = ((cofrag*8 + ch)*9 + kk)*64 + lane ; each entry = 8 bf16 (16B)
__global__ __launch_bounds__(256) void wperm_frag(const float* __restrict__ w,
                                                  short* __restrict__ wp) {
    const int i = blockIdx.x * 256 + threadIdx.x;   // 0..73727
    const int lane_w = i & 63;
    const int rest   = i >> 6;
    const int kk     = rest % 9;
    const int rest2  = rest / 9;
    const int ch     = rest2 & 7;
    const int cofrag = rest2 >> 3;                  // 0..15
    const int co     = cofrag * 16 + (lane_w & 15);
    const int cb     = ch * 32 + (lane_w >> 4) * 8;
    short8 v;
#pragma unroll
    for (int j = 0; j < 8; ++j)
        v[j] = f2bf(w[((size_t)co * C_ + cb + j) * KK_ + kk]);
    *reinterpret_cast<short8*>(wp + (size_t)i * 8) = v;
}

// ---- prepass 2: x NCHW fp32 -> NHWC bf16 ----
__global__ __launch_bounds__(256) void xpose(const float* __restrict__ x,
                                             short* __restrict__ xT) {
    __shared__ short tile[64 * 258];
    const int bid = blockIdx.x;          // 512 = 64*8
    const int y = bid & 63;
    const int b = bid >> 6;
    const int t = threadIdx.x;
    const int c4 = t >> 6;
    const int xw = t & 63;
    const float* src = x + (size_t)b * (C_ * H_ * W_) + (size_t)y * W_ + xw;
#pragma unroll 8
    for (int j = 0; j < 64; ++j) {
        const int c = j * 4 + c4;
        tile[xw * 258 + c] = f2bf(src[(size_t)c * (H_ * W_)]);
    }
    __syncthreads();
    short* dst = xT + ((size_t)(b * (H_ * W_)) + y * W_) * C_;
#pragma unroll
    for (int r = 0; r < 8; ++r) {
        const int idx = r * 256 + t;
        const int xw2 = idx >> 5;
        const int c2  = (idx & 31) * 8;
        *reinterpret_cast<short8*>(dst + xw2 * C_ + c2) =
            *reinterpret_cast<const short8*>(&tile[xw2 * 258 + c2]);
    }
}

// ---- main ----
__global__ __launch_bounds__(1024, 8) void dcn_mfma11(
    const short* __restrict__ xT,      // [b][y][x][c] bf16, 2MB/batch
    const float* __restrict__ offset,
    const short* __restrict__ wfr,     // A-fragment-ordered bf16 weights
    const float* __restrict__ bias,
    float* __restrict__ out)
{
    __shared__ uint32_t t_cp [KK_ * 64];   // x0|y0<<6|x1<<12|y1<<18
    __shared__ uint32_t t_w01[KK_ * 64];   // bf16(wv0) | bf16(wv1)<<16
    __shared__ uint32_t t_w23[KK_ * 64];   // bf16(wv2) | bf16(wv3)<<16
    __shared__ short    colsF[2][BUFSZ];   // dbuf, B-frag order [pxfrag][kk][1KB]

    const int bid = blockIdx.x;          // 512
    const int b   = bid & 7;             // XCD affinity per batch
    const int ho  = bid >> 3;

    const int t    = threadIdx.x;
    const int lane = t & 63;
    const int wave = t >> 6;             // 0..15

    // ---- bilinear tables: one entry per (kk, wo) ----
    if (t < KK_ * 64) {
        const int e  = t;
        const int kk = e >> 6;
        const int wo = e & 63;
        const int ky = kk / 3, kx = kk % 3;
        const float offy = offset[(((b * 18) + kk * 2 + 0) * 64 + ho) * 64 + wo];
        const float offx = offset[(((b * 18) + kk * 2 + 1) * 64 + ho) * 64 + wo];
        const float py  = (float)(ho - 1 + ky) + offy;
        const float pxx = (float)(wo - 1 + kx) + offx;
        const float y0f = floorf(py), x0f = floorf(pxx);
        const float wy = py - y0f, wx = pxx - x0f;
        const int y0 = (int)y0f, x0 = (int)x0f;
        const int y1 = y0 + 1,   x1 = x0 + 1;
        const float vy0 = (y0 >= 0 && y0 < H_) ? 1.f : 0.f;
        const float vy1 = (y1 >= 0 && y1 < H_) ? 1.f : 0.f;
        const float vx0 = (x0 >= 0 && x0 < W_) ? 1.f : 0.f;
        const float vx1 = (x1 >= 0 && x1 < W_) ? 1.f : 0.f;
        const float wv0 = (1.f - wy) * (1.f - wx) * vy0 * vx0;
        const float wv1 = (1.f - wy) * wx         * vy0 * vx1;
        const float wv2 = wy         * (1.f - wx) * vy1 * vx0;
        const float wv3 = wy         * wx         * vy1 * vx1;
        const int y0c = min(max(y0, 0), H_ - 1);
        const int y1c = min(max(y1, 0), H_ - 1);
        const int x0c = min(max(x0, 0), W_ - 1);
        const int x1c = min(max(x1, 0), W_ - 1);
        t_cp[e]  = (uint32_t)x0c | ((uint32_t)y0c << 6)
                 | ((uint32_t)x1c << 12) | ((uint32_t)y1c << 18);
        t_w01[e] = (uint32_t)(uint16_t)f2bf(wv0)
                 | ((uint32_t)(uint16_t)f2bf(wv1) << 16);
        t_w23[e] = (uint32_t)(uint16_t)f2bf(wv2)
                 | ((uint32_t)(uint16_t)f2bf(wv3) << 16);
    }
    __syncthreads();

    f32x4 acc00 = (f32x4)0.f, acc01 = (f32x4)0.f;
    f32x4 acc10 = (f32x4)0.f, acc11 = (f32x4)0.f;

    const int cog = wave >> 1;           // co-32 group (0..7)
    const int pxg = wave & 1;            // px-32 group
    const int m_l = lane & 15;

    // A-frag bases (global, coalesced 1KB rows)
    const short* af0b = wfr + ((size_t)(cog * 2 + 0) * 8) * 9 * 512 + lane * 8;
    const short* af1b = wfr + ((size_t)(cog * 2 + 1) * 8) * 9 * 512 + lane * 8;
    // B-frag element offsets within a cols buffer
    const int bfo0 = ((pxg * 2 + 0) * 9) * 512 + lane * 8;
    const int bfo1 = ((pxg * 2 + 1) * 9) * 512 + lane * 8;

    // staging ids: thread -> (px, ch-octet, tap-replica)
    const int soct = t & 3;              // channel octet (8 ch)
    const int spx  = (t >> 2) & 63;      // px
    const int srep = t >> 8;             // 0..3: taps {srep, srep+4, (srep==0: 8)}
    const uint32_t socto = (uint32_t)(soct * 16);
    const char* xbase = (const char*)xT + ((size_t)b << 21);
    const int cwo = ((spx >> 4) * 9) * 512 + ((spx & 15) + (soct << 4)) * 8;
    const int e0 = srep * 64 + spx;
    const int e1 = (srep + 4) * 64 + spx;
    const int e2 = 8 * 64 + spx;
    const int kk0v = srep;
    const int kk1v = srep + 4;

#define GTASK(EIDX, KKI, XC, DBUF) { \
    const uint32_t cp  = t_cp[EIDX]; \
    const uint32_t w01 = t_w01[EIDX]; \
    const uint32_t w23 = t_w23[EIDX]; \
    const uint32_t q00 = ((cp & 0xFFFu) << 9) + socto; \
    const uint32_t q01 = (((cp & 0xFC0u) | ((cp >> 12) & 63u)) << 9) + socto; \
    const uint32_t q10 = (((((cp >> 12) & 0xFC0u)) | (cp & 63u)) << 9) + socto; \
    const uint32_t q11 = (((cp >> 12) & 0xFFFu) << 9) + socto; \
    short8 s00, s01, s10, s11; \
    __builtin_memcpy(&s00, (XC) + q00, 16); \
    __builtin_memcpy(&s01, (XC) + q01, 16); \
    __builtin_memcpy(&s10, (XC) + q10, 16); \
    __builtin_memcpy(&s11, (XC) + q11, 16); \
    const float wv0 = lof(w01), wv1 = hif(w01); \
    const float wv2 = lof(w23), wv3 = hif(w23); \
    short8 vs; \
    _Pragma("unroll") \
    for (int j = 0; j < 8; ++j) { \
        const float v = wv0 * bf2f(s00[j]) + wv1 * bf2f(s01[j]) \
                      + wv2 * bf2f(s10[j]) + wv3 * bf2f(s11[j]); \
        vs[j] = f2bf(v); \
    } \
    *reinterpret_cast<short8*>(&(DBUF)[cwo + (KKI) * 512]) = vs; }

// e0 split into issue-early load / write-late interp (T14)
#define LOAD0(XC) { \
    const uint32_t cp = t_cp[e0]; \
    const uint32_t q00 = ((cp & 0xFFFu) << 9) + socto; \
    const uint32_t q01 = (((cp & 0xFC0u) | ((cp >> 12) & 63u)) << 9) + socto; \
    const uint32_t q10 = (((((cp >> 12) & 0xFC0u)) | (cp & 63u)) << 9) + socto; \
    const uint32_t q11 = (((cp >> 12) & 0xFFFu) << 9) + socto; \
    __builtin_memcpy(&Pa00, (XC) + q00, 16); \
    __builtin_memcpy(&Pa01, (XC) + q01, 16); \
    __builtin_memcpy(&Pa10, (XC) + q10, 16); \
    __builtin_memcpy(&Pa11, (XC) + q11, 16); }

#define WRITE0(DBUF) { \
    const uint32_t w01 = t_w01[e0]; \
    const uint32_t w23 = t_w23[e0]; \
    const float wv0 = lof(w01), wv1 = hif(w01); \
    const float wv2 = lof(w23), wv3 = hif(w23); \
    short8 vs; \
    _Pragma("unroll") \
    for (int j = 0; j < 8; ++j) { \
        const float v = wv0 * bf2f(Pa00[j]) + wv1 * bf2f(Pa01[j]) \
                      + wv2 * bf2f(Pa10[j]) + wv3 * bf2f(Pa11[j]); \
        vs[j] = f2bf(v); \
    } \
    *reinterpret_cast<short8*>(&(DBUF)[cwo + kk0v * 512]) = vs; }

    short8 Pa00, Pa01, Pa10, Pa11;    // e0 payload (held across MFMA)

    // prologue: stage chunk 0 into buf 0 (fully inline)
    {
        const char* xci = xbase;
        GTASK(e0, kk0v, xci, colsF[0])
        GTASK(e1, kk1v, xci, colsF[0])
        if (srep == 0) { GTASK(e2, 8, xci, colsF[0]) }
    }
    __syncthreads();

    for (int ch = 0; ch < 8; ++ch) {
        short* dbuf = &colsF[(ch + 1) & 1][0];
        if (ch < 7) {
            const char* xci = xbase + (ch + 1) * 64;
            LOAD0(xci)                            // in flight across MFMA
            GTASK(e1, kk1v, xci, dbuf)            // inline (as r16)
            if (srep == 0) { GTASK(e2, 8, xci, dbuf) }
        }

        const short* bufr = &colsF[ch & 1][0];
        const short* a0 = af0b + (size_t)ch * 9 * 512;
        const short* a1 = af1b + (size_t)ch * 9 * 512;
#pragma unroll
        for (int kk = 0; kk < 9; ++kk) {
            short8 af0, af1, bf0, bf1;
            __builtin_memcpy(&af0, a0 + kk * 512, 16);
            __builtin_memcpy(&af1, a1 + kk * 512, 16);
            __builtin_memcpy(&bf0, bufr + bfo0 + kk * 512, 16);
            __builtin_memcpy(&bf1, bufr + bfo1 + kk * 512, 16);
            acc00 = __builtin_amdgcn_mfma_f32_16x16x32_bf16(af0, bf0, acc00, 0, 0, 0);
            acc01 = __builtin_amdgcn_mfma_f32_16x16x32_bf16(af0, bf1, acc01, 0, 0, 0);
            acc10 = __builtin_amdgcn_mfma_f32_16x16x32_bf16(af1, bf0, acc10, 0, 0, 0);
            acc11 = __builtin_amdgcn_mfma_f32_16x16x32_bf16(af1, bf1, acc11, 0, 0, 0);
        }

        if (ch < 7) { WRITE0(dbuf) }              // write-late (pre-barrier)
        __syncthreads();
    }
#undef GTASK
#undef LOAD0
#undef WRITE0

    // ---- epilogue ----
    const int r0 = (lane >> 4) << 2;
    const int co_b = cog * 32;
    const int px_b = pxg * 32;
#pragma unroll
    for (int r = 0; r < 4; ++r) {
        {   // mt = 0
            const int co = co_b + r0 + r;
            const float bv = bias[co];
            float* orow = out + ((size_t)(b * CO_ + co) * H_ + ho) * W_;
            orow[px_b + m_l]      = acc00[r] + bv;
            orow[px_b + 16 + m_l] = acc01[r] + bv;
        }
        {   // mt = 1
            const int co = co_b + 16 + r0 + r;
            const float bv = bias[co];
            float* orow = out + ((size_t)(b * CO_ + co) * H_ + ho) * W_;
            orow[px_b + m_l]      = acc10[r] + bv;
            orow[px_b + 16 + m_l] = acc11[r] + bv;
        }
    }
}

// ================= fallback (round-6 proven path, ws < 18 MB) =================
#define PADK 296
__global__ __launch_bounds__(256) void w2bf_fb(const float* __restrict__ w,
                                               short* __restrict__ wb, int n8) {
    const int i = blockIdx.x * 256 + threadIdx.x;
    if (i >= n8) return;
    const f32x4 a = *reinterpret_cast<const f32x4*>(w + (size_t)i * 8);
    const f32x4 bq = *reinterpret_cast<const f32x4*>(w + (size_t)i * 8 + 4);
    short8 v;
#pragma unroll
    for (int j = 0; j < 4; ++j) { v[j] = f2bf(a[j]); v[j + 4] = f2bf(bq[j]); }
    *reinterpret_cast<short8*>(wb + (size_t)i * 8) = v;
}

__global__ __launch_bounds__(512, 2) void dcn_mfma_fb(
    const float* __restrict__ x,
    const float* __restrict__ offset,
    const short* __restrict__ wbf,
    const float* __restrict__ bias,
    float* __restrict__ out)
{
    __shared__ uint32_t t_oab[KK_ * 64];
    __shared__ f32x4    t_wv[KK_ * 64];
    __shared__ short    colsf[64 * PADK];

    const int bid = blockIdx.x;
    const int ho  = bid & 63;
    const int b   = bid >> 6;
    const int t    = threadIdx.x;
    const int lane = t & 63;
    const int wave = t >> 6;

    for (int e = t; e < KK_ * 64; e += 512) {
        const int kk = e >> 6;
        const int wo = e & 63;
        const int ky = kk / 3, kx = kk % 3;
        const float offy = offset[(((b * 18) + kk * 2 + 0) * 64 + ho) * 64 + wo];
        const float offx = offset[(((b * 18) + kk * 2 + 1) * 64 + ho) * 64 + wo];
        const float py  = (float)(ho - 1 + ky) + offy;
        const float pxx = (float)(wo - 1 + kx) + offx;
        const float y0f = floorf(py), x0f = floorf(pxx);
        const float wy = py - y0f, wx = pxx - x0f;
        const int y0 = (int)y0f, x0 = (int)x0f;
        const int y1 = y0 + 1,   x1 = x0 + 1;
        const float vy0 = (y0 >= 0 && y0 < H_) ? 1.f : 0.f;
        const float vy1 = (y1 >= 0 && y1 < H_) ? 1.f : 0.f;
        const float vx0 = (x0 >= 0 && x0 < W_) ? 1.f : 0.f;
        const float vx1 = (x1 >= 0 && x1 < W_) ? 1.f : 0.f;
        const float wv0 = (1.f - wy) * (1.f - wx) * vy0 * vx0;
        const float wv1 = (1.f - wy) * wx         * vy0 * vx1;
        const float wv2 = wy         * (1.f - wx) * vy1 * vx0;
        const float wv3 = wy         * wx         * vy1 * vx1;
        const int y0c = min(max(y0, 0), H_ - 1);
        const int y1c = min(max(y1, 0), H_ - 1);
        const int x0c = min(max(x0, 0), W_ - 1);
        const int x1c = min(max(x1, 0), W_ - 1);
        const int pb  = min(max(x0, 0), W_ - 2);
        const float sA0 = (x0c == pb)     ? 1.f : 0.f;
        const float sB0 = (x1c == pb)     ? 1.f : 0.f;
        const float sA1 = (x0c == pb + 1) ? 1.f : 0.f;
        const float sB1 = (x1c == pb + 1) ? 1.f : 0.f;
        f32x4 wv;
        wv[0] = sA0 * wv0 + sB0 * wv1;
        wv[1] = sA1 * wv0 + sB1 * wv1;
        wv[2] = sA0 * wv2 + sB0 * wv3;
        wv[3] = sA1 * wv2 + sB1 * wv3;
        t_oab[e] = (uint32_t)((y0c * W_ + pb) * 4) |
                   ((uint32_t)((y1c * W_ + pb) * 4) << 16);
        t_wv[e] = wv;
    }
    __syncthreads();

    f32x4 acc[4][2];
#pragma unroll
    for (int i = 0; i < 4; ++i) { acc[i][0] = (f32x4)0.f; acc[i][1] = (f32x4)0.f; }

    const int wm = wave >> 1;
    const int wn = wave & 1;
    const int co0 = __builtin_amdgcn_readfirstlane(wm * 64);
    const int px0 = __builtin_amdgcn_readfirstlane(wn * 32);
    const int wqs = __builtin_amdgcn_readfirstlane(wave);
    const int m_l = lane & 15;
    const int k_l = (lane >> 4) << 3;

    const short* wrow[4];
#pragma unroll
    for (int mt = 0; mt < 4; ++mt)
        wrow[mt] = wbf + (size_t)(co0 + mt * 16 + m_l) * (C_ * KK_);

    for (int c0 = 0; c0 < C_; c0 += 32) {
        const char* xp[4];
#pragma unroll
        for (int dc = 0; dc < 4; ++dc)
            xp[dc] = (const char*)(x + ((size_t)(b * C_ + c0 + 4 * wqs + dc) << 12));
#pragma unroll
        for (int j = 0; j < 9; ++j) {
            short vs[4];
#pragma unroll
            for (int jj = 0; jj < 4; ++jj) {
                const int idx = j * 4 + jj;
                const int dc  = idx / 9;
                const int kk  = idx % 9;
                const uint32_t oab = t_oab[kk * 64 + lane];
                const f32x4    wv  = t_wv[kk * 64 + lane];
                struct { float a, b; } lo, hi;
                __builtin_memcpy(&lo, xp[dc] + (oab & 0xFFFFu), 8);
                __builtin_memcpy(&hi, xp[dc] + (oab >> 16), 8);
                vs[jj] = f2bf(wv[0] * lo.a + wv[1] * lo.b +
                              wv[2] * hi.a + wv[3] * hi.b);
            }
            short* cw = &colsf[lane * PADK + (wave * 9 + j) * 4];
            cw[0] = vs[0]; cw[1] = vs[1]; cw[2] = vs[2]; cw[3] = vs[3];
        }
        __syncthreads();
#pragma unroll
        for (int s = 0; s < 9; ++s) {
            const int krow = s * 32 + k_l;
            const short8 bfA = *reinterpret_cast<const short8*>(
                &colsf[(px0 + m_l) * PADK + krow]);
            const short8 bfB = *reinterpret_cast<const short8*>(
                &colsf[(px0 + 16 + m_l) * PADK + krow]);
            const int kglob = c0 * 9 + krow;
#pragma unroll
            for (int mt = 0; mt < 4; ++mt) {
                const short8 af = *reinterpret_cast<const short8*>(wrow[mt] + kglob);
                acc[mt][0] = __builtin_amdgcn_mfma_f32_16x16x32_bf16(
                    af, bfA, acc[mt][0], 0, 0, 0);
                acc[mt][1] = __builtin_amdgcn_mfma_f32_16x16x32_bf16(
                    af, bfB, acc[mt][1], 0, 0, 0);
            }
        }
        __syncthreads();
    }

    const int r0 = (lane >> 4) << 2;
#pragma unroll
    for (int mt = 0; mt < 4; ++mt) {
#pragma unroll
        for (int r = 0; r < 4; ++r) {
            const int co = co0 + mt * 16 + r0 + r;
            const float bv = bias[co];
            float* orow = out + ((size_t)(b * CO_ + co) * H_ + ho) * W_;
            orow[px0 + m_l]      = acc[mt][0][r] + bv;
            orow[px0 + 16 + m_l] = acc[mt][1][r] + bv;
        }
    }
}

extern "C" void kernel_launch(void* const* d_in, const int* in_sizes, int n_in,
                              void* d_out, int out_size, void* d_ws, size_t ws_size,
                              hipStream_t stream) {
    const float* x      = (const float*)d_in[0];
    const float* offset = (const float*)d_in[1];
    const float* weight = (const float*)d_in[2];
    const float* bias   = (const float*)d_in[3];
    float* out = (float*)d_out;
    (void)in_sizes; (void)n_in; (void)out_size;

    const size_t WPM_BYTES = (size_t)CO_ * C_ * KK_ * 2;          // 1,179,648
    const size_t XT_BYTES  = (size_t)B_ * H_ * W_ * C_ * 2;       // 16,777,216

    if (ws_size >= WPM_BYTES + XT_BYTES) {
        short* wfr = (short*)d_ws;
        short* xT  = (short*)((char*)d_ws + WPM_BYTES);
        hipLaunchKernelGGL(wperm_frag, dim3(288), dim3(256), 0, stream, weight, wfr);
        hipLaunchKernelGGL(xpose,      dim3(512), dim3(256), 0, stream, x, xT);
        hipLaunchKernelGGL(dcn_mfma11, dim3(512), dim3(1024), 0, stream,
                           xT, offset, wfr, bias, out);
    } else {
        short* wbf = (short*)d_ws;   // 1.18 MB
        hipLaunchKernelGGL(w2bf_fb, dim3(288), dim3(256), 0, stream,
                           weight, wbf, 73728);
        hipLaunchKernelGGL(dcn_mfma_fb, dim3(512), dim3(512), 0, stream,
                           x, offset, wbf, bias, out);
    }
}

// Round 19
// 84.658 us; speedup vs baseline: 1.1669x; 1.1669x over previous
//
#include <hip/hip_runtime.h>
#include <cstdint>
#include <cstddef>

// DeformConv2d B=8 C=256 H=W=64 Cout=256 K=3 s=1 p=1 d=1
// Round 19 = Round 16 VERBATIM (best: 87.0us total / 76.0us main) with the
// two independent prepasses merged into one 800-block kernel (saves a
// launch; bodies unchanged). r17/r18 post-mortems: staging is latency +
// L2-BW bound; VALU cuts are flat, cross-MFMA payloads spill (32-VGPR pin).
// Fallback (ws too small): round-6 proven kernel.

#define B_   8
#define C_   256
#define H_   64
#define W_   64
#define CO_  256
#define KK_  9
#define BUFSZ (4 * 9 * 512)          // shorts per cols buffer

typedef short    short8 __attribute__((ext_vector_type(8)));
typedef float    f32x4  __attribute__((ext_vector_type(4)));

__device__ inline short f2bf(float f) {   // round-to-nearest-even fp32->bf16
    uint32_t u = __builtin_bit_cast(uint32_t, f);
    u += 0x7FFFu + ((u >> 16) & 1u);
    return (short)(u >> 16);
}
__device__ inline float bf2f(short s) {
    return __builtin_bit_cast(float, (uint32_t)(uint16_t)s << 16);
}
__device__ inline float lof(uint32_t u) {
    return __builtin_bit_cast(float, u << 16);
}
__device__ inline float hif(uint32_t u) {
    return __builtin_bit_cast(float, u & 0xFFFF0000u);
}

// ---- merged prepass: blocks [0,288) = weight->A-frag bf16; [288,800) = xpose ----
// wperm: entry i = ((cofrag*8 + ch)*9 + kk)*64 + lane ; 8 bf16 (16B) each
// xpose: x NCHW fp32 -> NHWC bf16 (xT[b][y][x][c])
__global__ __launch_bounds__(256) void prep(const float* __restrict__ w,
                                            short* __restrict__ wp,
                                            const float* __restrict__ x,
                                            short* __restrict__ xT) {
    __shared__ short tile[64 * 258];
    const int blk = blockIdx.x;
    const int t   = threadIdx.x;
    if (blk < 288) {
        const int i = blk * 256 + t;                // 0..73727
        const int lane_w = i & 63;
        const int rest   = i >> 6;
        const int kk     = rest % 9;
        const int rest2  = rest / 9;
        const int ch     = rest2 & 7;
        const int cofrag = rest2 >> 3;              // 0..15
        const int co     = cofrag * 16 + (lane_w & 15);
        const int cb     = ch * 32 + (lane_w >> 4) * 8;
        short8 v;
#pragma unroll
        for (int j = 0; j < 8; ++j)
            v[j] = f2bf(w[((size_t)co * C_ + cb + j) * KK_ + kk]);
        *reinterpret_cast<short8*>(wp + (size_t)i * 8) = v;
    } else {
        const int bid = blk - 288;                  // 0..511
        const int y = bid & 63;
        const int b = bid >> 6;
        const int c4 = t >> 6;
        const int xw = t & 63;
        const float* src = x + (size_t)b * (C_ * H_ * W_) + (size_t)y * W_ + xw;
#pragma unroll 8
        for (int j = 0; j < 64; ++j) {
            const int c = j * 4 + c4;
            tile[xw * 258 + c] = f2bf(src[(size_t)c * (H_ * W_)]);
        }
        __syncthreads();
        short* dst = xT + ((size_t)(b * (H_ * W_)) + y * W_) * C_;
#pragma unroll
        for (int r = 0; r < 8; ++r) {
            const int idx = r * 256 + t;            // 0..2047 short8 groups
            const int xw2 = idx >> 5;
            const int c2  = (idx & 31) * 8;
            *reinterpret_cast<short8*>(dst + xw2 * C_ + c2) =
                *reinterpret_cast<const short8*>(&tile[xw2 * 258 + c2]);
        }
    }
}

// ---- main (r16 verbatim) ----
__global__ __launch_bounds__(1024, 8) void dcn_mfma9(
    const short* __restrict__ xT,      // [b][y][x][c] bf16, 2MB/batch
    const float* __restrict__ offset,
    const short* __restrict__ wfr,     // A-fragment-ordered bf16 weights
    const float* __restrict__ bias,
    float* __restrict__ out)
{
    __shared__ uint32_t t_cp [KK_ * 64];   // x0|y0<<6|x1<<12|y1<<18
    __shared__ uint32_t t_w01[KK_ * 64];   // bf16(wv0) | bf16(wv1)<<16
    __shared__ uint32_t t_w23[KK_ * 64];   // bf16(wv2) | bf16(wv3)<<16
    __shared__ short    colsF[2][BUFSZ];   // dbuf, B-frag order [pxfrag][kk][1KB]

    const int bid = blockIdx.x;          // 512
    const int b   = bid & 7;             // XCD affinity per batch
    const int ho  = bid >> 3;

    const int t    = threadIdx.x;
    const int lane = t & 63;
    const int wave = t >> 6;             // 0..15

    // ---- bilinear tables: one entry per (kk, wo) ----
    if (t < KK_ * 64) {
        const int e  = t;
        const int kk = e >> 6;
        const int wo = e & 63;
        const int ky = kk / 3, kx = kk % 3;
        const float offy = offset[(((b * 18) + kk * 2 + 0) * 64 + ho) * 64 + wo];
        const float offx = offset[(((b * 18) + kk * 2 + 1) * 64 + ho) * 64 + wo];
        const float py  = (float)(ho - 1 + ky) + offy;
        const float pxx = (float)(wo - 1 + kx) + offx;
        const float y0f = floorf(py), x0f = floorf(pxx);
        const float wy = py - y0f, wx = pxx - x0f;
        const int y0 = (int)y0f, x0 = (int)x0f;
        const int y1 = y0 + 1,   x1 = x0 + 1;
        const float vy0 = (y0 >= 0 && y0 < H_) ? 1.f : 0.f;
        const float vy1 = (y1 >= 0 && y1 < H_) ? 1.f : 0.f;
        const float vx0 = (x0 >= 0 && x0 < W_) ? 1.f : 0.f;
        const float vx1 = (x1 >= 0 && x1 < W_) ? 1.f : 0.f;
        const float wv0 = (1.f - wy) * (1.f - wx) * vy0 * vx0;
        const float wv1 = (1.f - wy) * wx         * vy0 * vx1;
        const float wv2 = wy         * (1.f - wx) * vy1 * vx0;
        const float wv3 = wy         * wx         * vy1 * vx1;
        const int y0c = min(max(y0, 0), H_ - 1);
        const int y1c = min(max(y1, 0), H_ - 1);
        const int x0c = min(max(x0, 0), W_ - 1);
        const int x1c = min(max(x1, 0), W_ - 1);
        t_cp[e]  = (uint32_t)x0c | ((uint32_t)y0c << 6)
                 | ((uint32_t)x1c << 12) | ((uint32_t)y1c << 18);
        t_w01[e] = (uint32_t)(uint16_t)f2bf(wv0)
                 | ((uint32_t)(uint16_t)f2bf(wv1) << 16);
        t_w23[e] = (uint32_t)(uint16_t)f2bf(wv2)
                 | ((uint32_t)(uint16_t)f2bf(wv3) << 16);
    }
    __syncthreads();

    f32x4 acc00 = (f32x4)0.f, acc01 = (f32x4)0.f;
    f32x4 acc10 = (f32x4)0.f, acc11 = (f32x4)0.f;

    const int cog = wave >> 1;           // co-32 group (0..7)
    const int pxg = wave & 1;            // px-32 group
    const int m_l = lane & 15;

    // A-frag bases (global, coalesced 1KB rows)
    const short* af0b = wfr + ((size_t)(cog * 2 + 0) * 8) * 9 * 512 + lane * 8;
    const short* af1b = wfr + ((size_t)(cog * 2 + 1) * 8) * 9 * 512 + lane * 8;
    // B-frag element offsets within a cols buffer
    const int bfo0 = ((pxg * 2 + 0) * 9) * 512 + lane * 8;
    const int bfo1 = ((pxg * 2 + 1) * 9) * 512 + lane * 8;

    // staging ids: thread -> (px, ch-octet, tap-replica)
    const int soct = t & 3;              // channel octet (8 ch)
    const int spx  = (t >> 2) & 63;      // px
    const int srep = t >> 8;             // 0..3: taps {srep, srep+4, (srep==0: 8)}
    const uint32_t socto = (uint32_t)(soct * 16);
    const char* xbase = (const char*)xT + ((size_t)b << 21);
    const int cwo = ((spx >> 4) * 9) * 512 + ((spx & 15) + (soct << 4)) * 8;
    const int e0 = srep * 64 + spx;
    const int e1 = (srep + 4) * 64 + spx;
    const int e2 = 8 * 64 + spx;
    const int kk0v = srep;
    const int kk1v = srep + 4;

#define GTASK(EIDX, KKI, XC, DBUF) { \
    const uint32_t cp  = t_cp[EIDX]; \
    const uint32_t w01 = t_w01[EIDX]; \
    const uint32_t w23 = t_w23[EIDX]; \
    const uint32_t q00 = ((cp & 0xFFFu) << 9) + socto; \
    const uint32_t q01 = (((cp & 0xFC0u) | ((cp >> 12) & 63u)) << 9) + socto; \
    const uint32_t q10 = (((((cp >> 12) & 0xFC0u)) | (cp & 63u)) << 9) + socto; \
    const uint32_t q11 = (((cp >> 12) & 0xFFFu) << 9) + socto; \
    short8 s00, s01, s10, s11; \
    __builtin_memcpy(&s00, (XC) + q00, 16); \
    __builtin_memcpy(&s01, (XC) + q01, 16); \
    __builtin_memcpy(&s10, (XC) + q10, 16); \
    __builtin_memcpy(&s11, (XC) + q11, 16); \
    const float wv0 = lof(w01), wv1 = hif(w01); \
    const float wv2 = lof(w23), wv3 = hif(w23); \
    short8 vs; \
    _Pragma("unroll") \
    for (int j = 0; j < 8; ++j) { \
        const float v = wv0 * bf2f(s00[j]) + wv1 * bf2f(s01[j]) \
                      + wv2 * bf2f(s10[j]) + wv3 * bf2f(s11[j]); \
        vs[j] = f2bf(v); \
    } \
    *reinterpret_cast<short8*>(&(DBUF)[cwo + (KKI) * 512]) = vs; }

#define STAGE(CI, DBUF) { \
    const char* xci = xbase + (CI) * 64; \
    GTASK(e0, kk0v, xci, DBUF) \
    GTASK(e1, kk1v, xci, DBUF) \
    if (srep == 0) { GTASK(e2, 8, xci, DBUF) } }

    // prologue: stage chunk 0 into buf 0
    STAGE(0, colsF[0])
    __syncthreads();

    for (int ch = 0; ch < 8; ++ch) {
        // issue next chunk's staging before MFMA (independent buffers;
        // waves drift across the single barrier -> stage/MFMA overlap)
        if (ch < 7) { STAGE(ch + 1, colsF[(ch + 1) & 1]) }

        const short* bufr = &colsF[ch & 1][0];
        const short* a0 = af0b + (size_t)ch * 9 * 512;
        const short* a1 = af1b + (size_t)ch * 9 * 512;
#pragma unroll
        for (int kk = 0; kk < 9; ++kk) {
            short8 af0, af1, bf0, bf1;
            __builtin_memcpy(&af0, a0 + kk * 512, 16);
            __builtin_memcpy(&af1, a1 + kk * 512, 16);
            __builtin_memcpy(&bf0, bufr + bfo0 + kk * 512, 16);
            __builtin_memcpy(&bf1, bufr + bfo1 + kk * 512, 16);
            acc00 = __builtin_amdgcn_mfma_f32_16x16x32_bf16(af0, bf0, acc00, 0, 0, 0);
            acc01 = __builtin_amdgcn_mfma_f32_16x16x32_bf16(af0, bf1, acc01, 0, 0, 0);
            acc10 = __builtin_amdgcn_mfma_f32_16x16x32_bf16(af1, bf0, acc10, 0, 0, 0);
            acc11 = __builtin_amdgcn_mfma_f32_16x16x32_bf16(af1, bf1, acc11, 0, 0, 0);
        }
        __syncthreads();
    }
#undef STAGE
#undef GTASK

    // ---- epilogue ----
    const int r0 = (lane >> 4) << 2;
    const int co_b = cog * 32;
    const int px_b = pxg * 32;
#pragma unroll
    for (int r = 0; r < 4; ++r) {
        {   // mt = 0
            const int co = co_b + r0 + r;
            const float bv = bias[co];
            float* orow = out + ((size_t)(b * CO_ + co) * H_ + ho) * W_;
            orow[px_b + m_l]      = acc00[r] + bv;
            orow[px_b + 16 + m_l] = acc01[r] + bv;
        }
        {   // mt = 1
            const int co = co_b + 16 + r0 + r;
            const float bv = bias[co];
            float* orow = out + ((size_t)(b * CO_ + co) * H_ + ho) * W_;
            orow[px_b + m_l]      = acc10[r] + bv;
            orow[px_b + 16 + m_l] = acc11[r] + bv;
        }
    }
}

// ================= fallback (round-6 proven path, ws < 18 MB) =================
#define PADK 296
__global__ __launch_bounds__(256) void w2bf_fb(const float* __restrict__ w,
                                               short* __restrict__ wb, int n8) {
    const int i = blockIdx.x * 256 + threadIdx.x;
    if (i >= n8) return;
    const f32x4 a = *reinterpret_cast<const f32x4*>(w + (size_t)i * 8);
    const f32x4 bq = *reinterpret_cast<const f32x4*>(w + (size_t)i * 8 + 4);
    short8 v;
#pragma unroll
    for (int j = 0; j < 4; ++j) { v[j] = f2bf(a[j]); v[j + 4] = f2bf(bq[j]); }
    *reinterpret_cast<short8*>(wb + (size_t)i * 8) = v;
}

__global__ __launch_bounds__(512, 2) void dcn_mfma_fb(
    const float* __restrict__ x,
    const float* __restrict__ offset,
    const short* __restrict__ wbf,
    const float* __restrict__ bias,
    float* __restrict__ out)
{
    __shared__ uint32_t t_oab[KK_ * 64];
    __shared__ f32x4    t_wv[KK_ * 64];
    __shared__ short    colsf[64 * PADK];

    const int bid = blockIdx.x;
    const int ho  = bid & 63;
    const int b   = bid >> 6;
    const int t    = threadIdx.x;
    const int lane = t & 63;
    const int wave = t >> 6;

    for (int e = t; e < KK_ * 64; e += 512) {
        const int kk = e >> 6;
        const int wo = e & 63;
        const int ky = kk / 3, kx = kk % 3;
        const float offy = offset[(((b * 18) + kk * 2 + 0) * 64 + ho) * 64 + wo];
        const float offx = offset[(((b * 18) + kk * 2 + 1) * 64 + ho) * 64 + wo];
        const float py  = (float)(ho - 1 + ky) + offy;
        const float pxx = (float)(wo - 1 + kx) + offx;
        const float y0f = floorf(py), x0f = floorf(pxx);
        const float wy = py - y0f, wx = pxx - x0f;
        const int y0 = (int)y0f, x0 = (int)x0f;
        const int y1 = y0 + 1,   x1 = x0 + 1;
        const float vy0 = (y0 >= 0 && y0 < H_) ? 1.f : 0.f;
        const float vy1 = (y1 >= 0 && y1 < H_) ? 1.f : 0.f;
        const float vx0 = (x0 >= 0 && x0 < W_) ? 1.f : 0.f;
        const float vx1 = (x1 >= 0 && x1 < W_) ? 1.f : 0.f;
        const float wv0 = (1.f - wy) * (1.f - wx) * vy0 * vx0;
        const float wv1 = (1.f - wy) * wx         * vy0 * vx1;
        const float wv2 = wy         * (1.f - wx) * vy1 * vx0;
        const float wv3 = wy         * wx         * vy1 * vx1;
        const int y0c = min(max(y0, 0), H_ - 1);
        const int y1c = min(max(y1, 0), H_ - 1);
        const int x0c = min(max(x0, 0), W_ - 1);
        const int x1c = min(max(x1, 0), W_ - 1);
        const int pb  = min(max(x0, 0), W_ - 2);
        const float sA0 = (x0c == pb)     ? 1.f : 0.f;
        const float sB0 = (x1c == pb)     ? 1.f : 0.f;
        const float sA1 = (x0c == pb + 1) ? 1.f : 0.f;
        const float sB1 = (x1c == pb + 1) ? 1.f : 0.f;
        f32x4 wv;
        wv[0] = sA0 * wv0 + sB0 * wv1;
        wv[1] = sA1 * wv0 + sB1 * wv1;
        wv[2] = sA0 * wv2 + sB0 * wv3;
        wv[3] = sA1 * wv2 + sB1 * wv3;
        t_oab[e] = (uint32_t)((y0c * W_ + pb) * 4) |
                   ((uint32_t)((y1c * W_ + pb) * 4) << 16);
        t_wv[e] = wv;
    }
    __syncthreads();

    f32x4 acc[4][2];
#pragma unroll
    for (int i = 0; i < 4; ++i) { acc[i][0] = (f32x4)0.f; acc[i][1] = (f32x4)0.f; }

    const int wm = wave >> 1;
    const int wn = wave & 1;
    const int co0 = __builtin_amdgcn_readfirstlane(wm * 64);
    const int px0 = __builtin_amdgcn_readfirstlane(wn * 32);
    const int wqs = __builtin_amdgcn_readfirstlane(wave);
    const int m_l = lane & 15;
    const int k_l = (lane >> 4) << 3;

    const short* wrow[4];
#pragma unroll
    for (int mt = 0; mt < 4; ++mt)
        wrow[mt] = wbf + (size_t)(co0 + mt * 16 + m_l) * (C_ * KK_);

    for (int c0 = 0; c0 < C_; c0 += 32) {
        const char* xp[4];
#pragma unroll
        for (int dc = 0; dc < 4; ++dc)
            xp[dc] = (const char*)(x + ((size_t)(b * C_ + c0 + 4 * wqs + dc) << 12));
#pragma unroll
        for (int j = 0; j < 9; ++j) {
            short vs[4];
#pragma unroll
            for (int jj = 0; jj < 4; ++jj) {
                const int idx = j * 4 + jj;
                const int dc  = idx / 9;
                const int kk  = idx % 9;
                const uint32_t oab = t_oab[kk * 64 + lane];
                const f32x4    wv  = t_wv[kk * 64 + lane];
                struct { float a, b; } lo, hi;
                __builtin_memcpy(&lo, xp[dc] + (oab & 0xFFFFu), 8);
                __builtin_memcpy(&hi, xp[dc] + (oab >> 16), 8);
                vs[jj] = f2bf(wv[0] * lo.a + wv[1] * lo.b +
                              wv[2] * hi.a + wv[3] * hi.b);
            }
            short* cw = &colsf[lane * PADK + (wave * 9 + j) * 4];
            cw[0] = vs[0]; cw[1] = vs[1]; cw[2] = vs[2]; cw[3] = vs[3];
        }
        __syncthreads();
#pragma unroll
        for (int s = 0; s < 9; ++s) {
            const int krow = s * 32 + k_l;
            const short8 bfA = *reinterpret_cast<const short8*>(
                &colsf[(px0 + m_l) * PADK + krow]);
            const short8 bfB = *reinterpret_cast<const short8*>(
                &colsf[(px0 + 16 + m_l) * PADK + krow]);
            const int kglob = c0 * 9 + krow;
#pragma unroll
            for (int mt = 0; mt < 4; ++mt) {
                const short8 af = *reinterpret_cast<const short8*>(wrow[mt] + kglob);
                acc[mt][0] = __builtin_amdgcn_mfma_f32_16x16x32_bf16(
                    af, bfA, acc[mt][0], 0, 0, 0);
                acc[mt][1] = __builtin_amdgcn_mfma_f32_16x16x32_bf16(
                    af, bfB, acc[mt][1], 0, 0, 0);
            }
        }
        __syncthreads();
    }

    const int r0 = (lane >> 4) << 2;
#pragma unroll
    for (int mt = 0; mt < 4; ++mt) {
#pragma unroll
        for (int r = 0; r < 4; ++r) {
            const int co = co0 + mt * 16 + r0 + r;
            const float bv = bias[co];
            float* orow = out + ((size_t)(b * CO_ + co) * H_ + ho) * W_;
            orow[px0 + m_l]      = acc[mt][0][r] + bv;
            orow[px0 + 16 + m_l] = acc[mt][1][r] + bv;
        }
    }
}

extern "C" void kernel_launch(void* const* d_in, const int* in_sizes, int n_in,
                              void* d_out, int out_size, void* d_ws, size_t ws_size,
                              hipStream_t stream) {
    const float* x      = (const float*)d_in[0];
    const float* offset = (const float*)d_in[1];
    const float* weight = (const float*)d_in[2];
    const float* bias   = (const float*)d_in[3];
    float* out = (float*)d_out;
    (void)in_sizes; (void)n_in; (void)out_size;

    const size_t WPM_BYTES = (size_t)CO_ * C_ * KK_ * 2;          // 1,179,648
    const size_t XT_BYTES  = (size_t)B_ * H_ * W_ * C_ * 2;       // 16,777,216

    if (ws_size >= WPM_BYTES + XT_BYTES) {
        short* wfr = (short*)d_ws;
        short* xT  = (short*)((char*)d_ws + WPM_BYTES);
        hipLaunchKernelGGL(prep, dim3(288 + 512), dim3(256), 0, stream,
                           weight, wfr, x, xT);
        hipLaunchKernelGGL(dcn_mfma9, dim3(512), dim3(1024), 0, stream,
                           xT, offset, wfr, bias, out);
    } else {
        short* wbf = (short*)d_ws;   // 1.18 MB
        hipLaunchKernelGGL(w2bf_fb, dim3(288), dim3(256), 0, stream,
                           weight, wbf, 73728);
        hipLaunchKernelGGL(dcn_mfma_fb, dim3(512), dim3(512), 0, stream,
                           x, offset, wbf, bias, out);
    }
}